// Round 1
// baseline (27109.305 us; speedup 1.0000x reference)
//
#include <hip/hip_runtime.h>
#include <math.h>

// Sizes fixed by the problem
#define B_SZ 64
#define T_SZ 512
#define IN_SZ 16
#define H_SZ 512
#define G_SZ 1536   // 3*H
#define J_SZ 8

// ---------------------------------------------------------------------------
// transpose: src [R][C] row-major -> dst [C][R]  (dst[c*R+r] = src[r*C+c])
__global__ void k_transpose(const float* __restrict__ src, float* __restrict__ dst,
                            int R, int C) {
    int i = blockIdx.x * 256 + threadIdx.x;
    if (i < R * C) {
        int r = i / C, c = i % C;
        dst[c * R + r] = src[i];
    }
}

// init persistent state from inputs (ws is re-poisoned before every call)
__global__ void k_init(const float* __restrict__ h0in, const float* __restrict__ th0,
                       const float* __restrict__ om0,
                       float* __restrict__ h0s, float* __restrict__ h1s,
                       float* __restrict__ ths, float* __restrict__ oms) {
    int i = blockIdx.x * 256 + threadIdx.x;
    if (i < 32768)       h0s[i]          = h0in[i];
    else if (i < 65536)  h1s[i - 32768]  = h0in[i];
    else if (i < 66048)  ths[i - 65536]  = th0[i - 65536];
    else if (i < 66560)  oms[i - 66048]  = om0[i - 66048];
}

// ---------------------------------------------------------------------------
// Pass A: layer-0 GRU recurrence. One WG per batch element, 512 threads.
// Thread t owns h-column t: gates r,z,n are rows t, 512+t, 1024+t.
// Weights are k-major transposed (WT0[k][g]) so lane reads are coalesced.
__global__ __launch_bounds__(512)
void k_pass_a(const float* __restrict__ x, const float* __restrict__ WT0,
              const float* __restrict__ WTi0,
              const float* __restrict__ b_ih0, const float* __restrict__ b_hh0,
              float* __restrict__ h0_state, float* __restrict__ h0c,
              int t0, int TC) {
    int b = blockIdx.x, t = threadIdx.x;
    __shared__ float hs[H_SZ];
    __shared__ float xs[IN_SZ];
    hs[t] = h0_state[b * H_SZ + t];
    float bir = b_ih0[t], biz = b_ih0[512 + t], bin_ = b_ih0[1024 + t];
    float bhr = b_hh0[t], bhz = b_hh0[512 + t], bhn = b_hh0[1024 + t];
    __syncthreads();
    for (int tt = 0; tt < TC; ++tt) {
        if (t < IN_SZ) xs[t] = x[(size_t)(b * T_SZ + t0 + tt) * IN_SZ + t];
        __syncthreads();
        // x path (tiny)
        float ir = bir, iz = biz, in_ = bin_;
        {
            const float* w = WTi0 + t;
            #pragma unroll
            for (int k = 0; k < IN_SZ; ++k) {
                float xk = xs[k];
                ir += w[0] * xk; iz += w[512] * xk; in_ += w[1024] * xk;
                w += G_SZ;
            }
        }
        // h path (the real work)
        float hr = bhr, hz = bhz, hn = bhn;
        {
            const float* w = WT0 + t;
            #pragma unroll 8
            for (int k = 0; k < H_SZ; ++k) {
                float hk = hs[k];
                hr += w[0] * hk; hz += w[512] * hk; hn += w[1024] * hk;
                w += G_SZ;
            }
        }
        float r = 1.f / (1.f + expf(-(ir + hr)));
        float z = 1.f / (1.f + expf(-(iz + hz)));
        float n = tanhf(in_ + r * hn);
        __syncthreads();                       // all reads of hs done
        float hnew = (1.f - z) * n + z * hs[t];
        hs[t] = hnew;
        h0c[(size_t)(tt * B_SZ + b) * H_SZ + t] = hnew;
        __syncthreads();                       // hs visible for next step
    }
    h0_state[b * H_SZ + t] = hs[t];
}

// ---------------------------------------------------------------------------
// K2: gi1c[M][1536] = h0c[M][512] @ W_ih1[1536][512]^T + b_ih1  (NT fp32 GEMM)
// 128x128 tile, K-step 16, 256 threads, 8x8 micro-tile.
__global__ __launch_bounds__(256)
void k_gemm(const float* __restrict__ A, const float* __restrict__ Bw,
            const float* __restrict__ bias, float* __restrict__ C) {
    __shared__ float As[16][132];
    __shared__ float Bs[16][132];
    int tid = threadIdx.x;
    int bm = blockIdx.x, bn = blockIdx.y;
    int ty = tid >> 4, tx = tid & 15;
    int m0 = ty * 8, n0 = tx * 8;
    float acc[8][8];
    #pragma unroll
    for (int i = 0; i < 8; ++i)
        #pragma unroll
        for (int j = 0; j < 8; ++j) acc[i][j] = 0.f;
    const float* Ab = A + (size_t)bm * 128 * 512;
    const float* Bb = Bw + (size_t)bn * 128 * 512;
    for (int k0 = 0; k0 < 512; k0 += 16) {
        __syncthreads();
        #pragma unroll
        for (int s = 0; s < 2; ++s) {
            int q = tid * 2 + s;          // 0..511
            int m = q >> 2, kq = q & 3;
            float4 av = *(const float4*)(Ab + (size_t)m * 512 + k0 + kq * 4);
            As[kq * 4 + 0][m] = av.x; As[kq * 4 + 1][m] = av.y;
            As[kq * 4 + 2][m] = av.z; As[kq * 4 + 3][m] = av.w;
            float4 bv = *(const float4*)(Bb + (size_t)m * 512 + k0 + kq * 4);
            Bs[kq * 4 + 0][m] = bv.x; Bs[kq * 4 + 1][m] = bv.y;
            Bs[kq * 4 + 2][m] = bv.z; Bs[kq * 4 + 3][m] = bv.w;
        }
        __syncthreads();
        #pragma unroll
        for (int kk = 0; kk < 16; ++kk) {
            float a[8], bb[8];
            float4 a0 = *(const float4*)&As[kk][m0];
            float4 a1 = *(const float4*)&As[kk][m0 + 4];
            float4 b0 = *(const float4*)&Bs[kk][n0];
            float4 b1 = *(const float4*)&Bs[kk][n0 + 4];
            a[0]=a0.x; a[1]=a0.y; a[2]=a0.z; a[3]=a0.w;
            a[4]=a1.x; a[5]=a1.y; a[6]=a1.z; a[7]=a1.w;
            bb[0]=b0.x; bb[1]=b0.y; bb[2]=b0.z; bb[3]=b0.w;
            bb[4]=b1.x; bb[5]=b1.y; bb[6]=b1.z; bb[7]=b1.w;
            #pragma unroll
            for (int i = 0; i < 8; ++i)
                #pragma unroll
                for (int j = 0; j < 8; ++j)
                    acc[i][j] += a[i] * bb[j];
        }
    }
    #pragma unroll
    for (int i = 0; i < 8; ++i) {
        size_t crow = (size_t)(bm * 128 + m0 + i) * G_SZ + bn * 128 + n0;
        #pragma unroll
        for (int j = 0; j < 8; ++j)
            C[crow + j] = acc[i][j] + bias[bn * 128 + n0 + j];
    }
}

// ---------------------------------------------------------------------------
// Pass B: layer-1 GRU recurrence + FC + biophysics. One WG per batch element.
__global__ __launch_bounds__(512)
void k_pass_b(const float* __restrict__ gi1c, const float* __restrict__ WT1,
              const float* __restrict__ b_hh1, const float* __restrict__ fc_W,
              const float* __restrict__ fc_b,
              float* __restrict__ h1_state, float* __restrict__ th_state,
              float* __restrict__ om_state, float* __restrict__ out,
              int t0, int TC) {
    int b = blockIdx.x, t = threadIdx.x;
    __shared__ float hs[H_SZ];
    __shared__ float fcw[16 * H_SZ];
    __shared__ float apre[16];
    hs[t] = h1_state[b * H_SZ + t];
    for (int i = t; i < 16 * H_SZ; i += 512) fcw[i] = fc_W[i];
    float bhr = b_hh1[t], bhz = b_hh1[512 + t], bhn = b_hh1[1024 + t];
    float th = 0.f, om = 0.f, fb0 = 0.f, fb1 = 0.f;
    if (t < J_SZ) {
        th = th_state[b * J_SZ + t];
        om = om_state[b * J_SZ + t];
        fb0 = fc_b[2 * t]; fb1 = fc_b[2 * t + 1];
    }
    int lane = t & 63, wv = t >> 6, l = lane & 31;
    int o = wv * 2 + (lane >> 5);    // FC output this half-wave reduces
    __syncthreads();
    for (int tt = 0; tt < TC; ++tt) {
        size_t row = (size_t)(tt * B_SZ + b) * G_SZ;
        float ir = gi1c[row + t];
        float iz = gi1c[row + 512 + t];
        float in_ = gi1c[row + 1024 + t];
        float hr = bhr, hz = bhz, hn = bhn;
        const float* w = WT1 + t;
        #pragma unroll 8
        for (int k = 0; k < H_SZ; ++k) {
            float hk = hs[k];
            hr += w[0] * hk; hz += w[512] * hk; hn += w[1024] * hk;
            w += G_SZ;
        }
        float r = 1.f / (1.f + expf(-(ir + hr)));
        float z = 1.f / (1.f + expf(-(iz + hz)));
        float n = tanhf(in_ + r * hn);
        __syncthreads();
        float hnew = (1.f - z) * n + z * hs[t];
        hs[t] = hnew;
        __syncthreads();
        // FC: half-wave (32 lanes) per output o; shuffle-reduce
        float p = 0.f;
        const float* fw = fcw + o * H_SZ;
        #pragma unroll
        for (int i = 0; i < 16; ++i) { int k = l + 32 * i; p += hs[k] * fw[k]; }
        p += __shfl_xor(p, 16);
        p += __shfl_xor(p, 8);
        p += __shfl_xor(p, 4);
        p += __shfl_xor(p, 2);
        p += __shfl_xor(p, 1);
        if (l == 0) apre[o] = p;
        __syncthreads();
        if (t < J_SZ) {
            float a0 = 1.f / (1.f + expf(-(apre[2 * t] + fb0)));
            float a1 = 1.f / (1.f + expf(-(apre[2 * t + 1] + fb1)));
            // F = (K0+K1*a)*(L0+L1*a - ma*th), ma = {-0.05, +0.05}
            float F0 = (100.f + 2000.f * a0) * (0.06f + 0.006f * a0 + 0.05f * th);
            float F1 = (100.f + 2000.f * a1) * (0.06f + 0.006f * a1 - 0.05f * th);
            float tau = 0.05f * (F1 - F0);
            float acc = (tau - 5.f * th - 0.3f * om) / 0.004f;
            om += (1.0f / 60.0f) * acc;
            th += (1.0f / 60.0f) * om;
            out[(size_t)(b * T_SZ + t0 + tt) * J_SZ + t] = th;
        }
        __syncthreads();
    }
    h1_state[b * H_SZ + t] = hs[t];
    if (t < J_SZ) {
        th_state[b * J_SZ + t] = th;
        om_state[b * J_SZ + t] = om;
    }
}

// ---------------------------------------------------------------------------
extern "C" void kernel_launch(void* const* d_in, const int* in_sizes, int n_in,
                              void* d_out, int out_size, void* d_ws, size_t ws_size,
                              hipStream_t stream) {
    const float* x     = (const float*)d_in[0];   // [64,512,16]
    const float* W_ih0 = (const float*)d_in[1];   // [1536,16]
    const float* W_hh0 = (const float*)d_in[2];   // [1536,512]
    const float* b_ih0 = (const float*)d_in[3];   // [1536]
    const float* b_hh0 = (const float*)d_in[4];
    const float* W_ih1 = (const float*)d_in[5];   // [1536,512]
    const float* W_hh1 = (const float*)d_in[6];   // [1536,512]
    const float* b_ih1 = (const float*)d_in[7];
    const float* b_hh1 = (const float*)d_in[8];
    const float* fc_W  = (const float*)d_in[9];   // [16,512]
    const float* fc_b  = (const float*)d_in[10];  // [16]
    const float* h0    = (const float*)d_in[11];  // [2,64,512]
    const float* th0   = (const float*)d_in[12];  // [64,8]
    const float* om0   = (const float*)d_in[13];  // [64,8]
    float* out = (float*)d_out;

    float* ws = (float*)d_ws;
    size_t off = 0;
    float* WT0  = ws + off; off += (size_t)H_SZ * G_SZ;   // [512][1536]
    float* WT1  = ws + off; off += (size_t)H_SZ * G_SZ;
    float* WTi0 = ws + off; off += (size_t)IN_SZ * G_SZ;  // [16][1536]
    float* h0s  = ws + off; off += (size_t)B_SZ * H_SZ;
    float* h1s  = ws + off; off += (size_t)B_SZ * H_SZ;
    float* ths  = ws + off; off += (size_t)B_SZ * J_SZ;
    float* oms  = ws + off; off += (size_t)B_SZ * J_SZ;
    size_t fixed_bytes = off * sizeof(float);

    // chunk length over T, picked deterministically from ws_size
    int TC = 8;
    const int cands[4] = {128, 64, 32, 16};
    for (int ci = 0; ci < 4; ++ci) {
        size_t need = fixed_bytes +
            (size_t)cands[ci] * B_SZ * (H_SZ + G_SZ) * sizeof(float);
        if (need <= ws_size) { TC = cands[ci]; break; }
    }
    float* h0c  = ws + off;                          // [TC*64][512]
    float* gi1c = h0c + (size_t)TC * B_SZ * H_SZ;    // [TC*64][1536]

    k_transpose<<<(G_SZ * H_SZ + 255) / 256, 256, 0, stream>>>(W_hh0, WT0, G_SZ, H_SZ);
    k_transpose<<<(G_SZ * H_SZ + 255) / 256, 256, 0, stream>>>(W_hh1, WT1, G_SZ, H_SZ);
    k_transpose<<<(G_SZ * IN_SZ + 255) / 256, 256, 0, stream>>>(W_ih0, WTi0, G_SZ, IN_SZ);
    k_init<<<(66560 + 255) / 256, 256, 0, stream>>>(h0, th0, om0, h0s, h1s, ths, oms);

    for (int t0 = 0; t0 < T_SZ; t0 += TC) {
        k_pass_a<<<B_SZ, 512, 0, stream>>>(x, WT0, WTi0, b_ih0, b_hh0, h0s, h0c, t0, TC);
        dim3 g(TC * B_SZ / 128, G_SZ / 128);
        k_gemm<<<g, 256, 0, stream>>>(h0c, W_ih1, b_ih1, gi1c);
        k_pass_b<<<B_SZ, 512, 0, stream>>>(gi1c, WT1, b_hh1, fc_W, fc_b,
                                           h1s, ths, oms, out, t0, TC);
    }
}

// Round 3
// 18080.067 us; speedup vs baseline: 1.4994x; 1.4994x over previous
//
#include <hip/hip_runtime.h>
#include <math.h>

#define B_SZ 64
#define T_SZ 512
#define IN_SZ 16
#define H_SZ 512
#define G_SZ 1536
#define J_SZ 8
#define NWG 128
#define NTH 512

// ---------------------------------------------------------------------------
// device-scope grid barrier (requires cooperative launch, gen starts at 1)
__device__ __forceinline__ void grid_barrier(unsigned* cnt, unsigned* flag, unsigned gen) {
    __syncthreads();
    if (threadIdx.x == 0) {
        __threadfence();
        unsigned prev = __hip_atomic_fetch_add(cnt, 1u, __ATOMIC_RELAXED, __HIP_MEMORY_SCOPE_AGENT);
        if (prev + 1u == (unsigned)NWG * gen) {
            __hip_atomic_store(flag, gen, __ATOMIC_RELAXED, __HIP_MEMORY_SCOPE_AGENT);
        } else {
            unsigned f;
            do {
                __builtin_amdgcn_s_sleep(1);
                f = __hip_atomic_load(flag, __ATOMIC_RELAXED, __HIP_MEMORY_SCOPE_AGENT);
            } while (f < gen);
        }
        __threadfence();
    }
    __syncthreads();
}

// ---------------------------------------------------------------------------
// init: h0 layer0 -> h0c[TC-1], h0 layer1 -> h1buf parity 1, th/om, zero barriers
__global__ void k_init(const float* __restrict__ h0in, const float* __restrict__ th0,
                       const float* __restrict__ om0, float* __restrict__ h0c,
                       float* __restrict__ h1buf, float* __restrict__ ths,
                       float* __restrict__ oms, unsigned* __restrict__ bar, int TC) {
    int i = blockIdx.x * 256 + threadIdx.x;
    if (i < 32768)       h0c[(size_t)(TC - 1) * 32768 + i] = h0in[i];
    else if (i < 65536)  h1buf[i] = h0in[i];           // parity-1 region is [32768,65536)
    else if (i < 66048)  ths[i - 65536] = th0[i - 65536];
    else if (i < 66560)  oms[i - 66048] = om0[i - 66048];
    else if (i < 67072)  bar[i - 66560] = 0u;
}

// ---------------------------------------------------------------------------
// Pass A: layer-0 GRU. Gate-column partitioned: WG w owns h-cols c0..c0+3
// (12 gate rows), lane = chain, 8 waves k-split the 512-dot by 64 each.
// Weight slice lives in LDS for the whole chunk.
__global__ __launch_bounds__(NTH)
void k_pass_a(const float* __restrict__ x, const float* __restrict__ Whh,
              const float* __restrict__ Wih, const float* __restrict__ bih,
              const float* __restrict__ bhh, float* __restrict__ h0c,
              unsigned* cnt, unsigned* flag, int t0, int TC) {
    const int w = blockIdx.x, tid = threadIdx.x;
    const int v = tid >> 6, m = tid & 63;
    const int c0 = w * 4;
    __shared__ float wlds[12 * 512];
    __shared__ float wihs[12 * 16];
    __shared__ float pl[8 * 12 * 64];
    // stage W_hh slice: local gate g = gt*4+j -> global row gt*512 + c0 + j
    for (int i = tid; i < 12 * 128; i += NTH) {
        int g = i >> 7, q = i & 127;
        int row = (g >> 2) * 512 + c0 + (g & 3);
        *(float4*)&wlds[g * 512 + q * 4] = *(const float4*)(Whh + (size_t)row * 512 + q * 4);
    }
    for (int i = tid; i < 12 * 4; i += NTH) {
        int g = i >> 2, q = i & 3;
        int row = (g >> 2) * 512 + c0 + (g & 3);
        *(float4*)&wihs[g * 16 + q * 4] = *(const float4*)(Wih + (size_t)row * 16 + q * 4);
    }
    float b_r = 0.f, b_z = 0.f, b_in = 0.f, b_hn = 0.f;
    if (v < 4) {
        int c = c0 + v;
        b_r  = bih[c] + bhh[c];
        b_z  = bih[512 + c] + bhh[512 + c];
        b_in = bih[1024 + c];
        b_hn = bhh[1024 + c];
    }
    __syncthreads();
    const int ks = v * 64;
    for (int tt = 0; tt < TC; ++tt) {
        const float* hprev = h0c + (size_t)((tt + TC - 1) % TC) * 32768 + m * 512;
        float a[12];
        #pragma unroll
        for (int g = 0; g < 12; ++g) a[g] = 0.f;
        #pragma unroll
        for (int kk = 0; kk < 4; ++kk) {
            const float* hp = hprev + ks + kk * 16;
            float4 h0_ = *(const float4*)(hp + 0);
            float4 h1_ = *(const float4*)(hp + 4);
            float4 h2_ = *(const float4*)(hp + 8);
            float4 h3_ = *(const float4*)(hp + 12);
            #pragma unroll
            for (int g = 0; g < 12; ++g) {
                const float* wp = wlds + g * 512 + ks + kk * 16;
                float4 w0 = *(const float4*)(wp + 0);
                float4 w1 = *(const float4*)(wp + 4);
                float4 w2 = *(const float4*)(wp + 8);
                float4 w3 = *(const float4*)(wp + 12);
                a[g] += h0_.x*w0.x + h0_.y*w0.y + h0_.z*w0.z + h0_.w*w0.w
                      + h1_.x*w1.x + h1_.y*w1.y + h1_.z*w1.z + h1_.w*w1.w
                      + h2_.x*w2.x + h2_.y*w2.y + h2_.z*w2.z + h2_.w*w2.w
                      + h3_.x*w3.x + h3_.y*w3.y + h3_.z*w3.z + h3_.w*w3.w;
            }
        }
        #pragma unroll
        for (int g = 0; g < 12; ++g) pl[(v * 12 + g) * 64 + m] = a[g];
        __syncthreads();
        if (v < 4) {
            int c = c0 + v;
            float hr = 0.f, hz = 0.f, hn = 0.f;
            #pragma unroll
            for (int u = 0; u < 8; ++u) {
                hr += pl[(u * 12 + v) * 64 + m];
                hz += pl[(u * 12 + 4 + v) * 64 + m];
                hn += pl[(u * 12 + 8 + v) * 64 + m];
            }
            const float* xp = x + ((size_t)m * T_SZ + t0 + tt) * IN_SZ;
            float4 x0 = *(const float4*)(xp + 0);
            float4 x1 = *(const float4*)(xp + 4);
            float4 x2 = *(const float4*)(xp + 8);
            float4 x3 = *(const float4*)(xp + 12);
            float xv[16] = {x0.x,x0.y,x0.z,x0.w, x1.x,x1.y,x1.z,x1.w,
                            x2.x,x2.y,x2.z,x2.w, x3.x,x3.y,x3.z,x3.w};
            float ir = 0.f, iz = 0.f, in_ = 0.f;
            #pragma unroll
            for (int k = 0; k < 16; ++k) {
                ir  += wihs[(0 + v) * 16 + k] * xv[k];
                iz  += wihs[(4 + v) * 16 + k] * xv[k];
                in_ += wihs[(8 + v) * 16 + k] * xv[k];
            }
            float hold = hprev[c];
            float r = 1.f / (1.f + expf(-(ir + hr + b_r)));
            float z = 1.f / (1.f + expf(-(iz + hz + b_z)));
            float n = tanhf(in_ + b_in + r * (hn + b_hn));
            h0c[(size_t)tt * 32768 + m * 512 + c] = (1.f - z) * n + z * hold;
        }
        grid_barrier(cnt, flag, (unsigned)(tt + 1));
    }
}

// ---------------------------------------------------------------------------
// K2: giT[g][row] = (h0c[row][:] . W_ih1[g][:]) + b_ih1[g]   (NT fp32 GEMM,
// transposed epilogue so pass B gate reads are lane-coalesced)
__global__ __launch_bounds__(256)
void k_gemm(const float* __restrict__ A, const float* __restrict__ Bw,
            const float* __restrict__ bias, float* __restrict__ CT, int M) {
    __shared__ float As[16][132];
    __shared__ float Bs[16][132];
    int tid = threadIdx.x;
    int bm = blockIdx.x, bn = blockIdx.y;
    int ty = tid >> 4, tx = tid & 15;
    int m0 = ty * 8, n0 = tx * 8;
    float acc[8][8];
    #pragma unroll
    for (int i = 0; i < 8; ++i)
        #pragma unroll
        for (int j = 0; j < 8; ++j) acc[i][j] = 0.f;
    const float* Ab = A + (size_t)bm * 128 * 512;
    const float* Bb = Bw + (size_t)bn * 128 * 512;
    for (int k0 = 0; k0 < 512; k0 += 16) {
        __syncthreads();
        #pragma unroll
        for (int s = 0; s < 2; ++s) {
            int q = tid * 2 + s;
            int m = q >> 2, kq = q & 3;
            float4 av = *(const float4*)(Ab + (size_t)m * 512 + k0 + kq * 4);
            As[kq * 4 + 0][m] = av.x; As[kq * 4 + 1][m] = av.y;
            As[kq * 4 + 2][m] = av.z; As[kq * 4 + 3][m] = av.w;
            float4 bv = *(const float4*)(Bb + (size_t)m * 512 + k0 + kq * 4);
            Bs[kq * 4 + 0][m] = bv.x; Bs[kq * 4 + 1][m] = bv.y;
            Bs[kq * 4 + 2][m] = bv.z; Bs[kq * 4 + 3][m] = bv.w;
        }
        __syncthreads();
        #pragma unroll
        for (int kk = 0; kk < 16; ++kk) {
            float a[8], bb[8];
            float4 a0 = *(const float4*)&As[kk][m0];
            float4 a1 = *(const float4*)&As[kk][m0 + 4];
            float4 b0 = *(const float4*)&Bs[kk][n0];
            float4 b1 = *(const float4*)&Bs[kk][n0 + 4];
            a[0]=a0.x; a[1]=a0.y; a[2]=a0.z; a[3]=a0.w;
            a[4]=a1.x; a[5]=a1.y; a[6]=a1.z; a[7]=a1.w;
            bb[0]=b0.x; bb[1]=b0.y; bb[2]=b0.z; bb[3]=b0.w;
            bb[4]=b1.x; bb[5]=b1.y; bb[6]=b1.z; bb[7]=b1.w;
            #pragma unroll
            for (int i = 0; i < 8; ++i)
                #pragma unroll
                for (int j = 0; j < 8; ++j)
                    acc[i][j] += a[i] * bb[j];
        }
    }
    #pragma unroll
    for (int j = 0; j < 8; ++j) {
        int g = bn * 128 + n0 + j;
        float bv = bias[g];
        float4 lo = make_float4(acc[0][j]+bv, acc[1][j]+bv, acc[2][j]+bv, acc[3][j]+bv);
        float4 hi = make_float4(acc[4][j]+bv, acc[5][j]+bv, acc[6][j]+bv, acc[7][j]+bv);
        size_t base = (size_t)g * M + (size_t)bm * 128 + m0;
        *(float4*)(CT + base)     = lo;
        *(float4*)(CT + base + 4) = hi;
    }
}

// ---------------------------------------------------------------------------
// Pass B: layer-1 GRU (same partitioning) + FC + biophys (WGs 0..63, chain=w).
// h1 in a parity double-buffer so FC(t) overlaps the next step.
__global__ __launch_bounds__(NTH)
void k_pass_b(const float* __restrict__ giT, const float* __restrict__ Whh,
              const float* __restrict__ bhh, const float* __restrict__ fcW,
              const float* __restrict__ fcb, float* __restrict__ h1buf,
              float* __restrict__ ths, float* __restrict__ oms,
              float* __restrict__ out, unsigned* cnt, unsigned* flag,
              int t0, int TC) {
    const int w = blockIdx.x, tid = threadIdx.x;
    const int v = tid >> 6, m = tid & 63;
    const int c0 = w * 4;
    const int M = TC * 64;
    __shared__ float wlds[12 * 512];
    __shared__ float fcw[16 * 512];
    __shared__ float pl[8 * 12 * 64];
    __shared__ float apre[16];
    for (int i = tid; i < 12 * 128; i += NTH) {
        int g = i >> 7, q = i & 127;
        int row = (g >> 2) * 512 + c0 + (g & 3);
        *(float4*)&wlds[g * 512 + q * 4] = *(const float4*)(Whh + (size_t)row * 512 + q * 4);
    }
    if (w < 64)
        for (int i = tid; i < 16 * 128; i += NTH)
            *(float4*)&fcw[i * 4] = *(const float4*)(fcW + (size_t)i * 4);
    float b_r = 0.f, b_z = 0.f, b_hn = 0.f;
    if (v < 4) {
        int c = c0 + v;
        b_r = bhh[c]; b_z = bhh[512 + c]; b_hn = bhh[1024 + c];
    }
    float th = 0.f, om = 0.f, fb0 = 0.f, fb1 = 0.f;
    if (tid < J_SZ && w < 64) {
        th = ths[w * J_SZ + tid]; om = oms[w * J_SZ + tid];
        fb0 = fcb[2 * tid]; fb1 = fcb[2 * tid + 1];
    }
    __syncthreads();
    const int ks = v * 64;
    for (int tt = 0; tt < TC; ++tt) {
        const float* hprev = h1buf + ((tt + 1) & 1) * 32768 + m * 512;
        float a[12];
        #pragma unroll
        for (int g = 0; g < 12; ++g) a[g] = 0.f;
        #pragma unroll
        for (int kk = 0; kk < 4; ++kk) {
            const float* hp = hprev + ks + kk * 16;
            float4 h0_ = *(const float4*)(hp + 0);
            float4 h1_ = *(const float4*)(hp + 4);
            float4 h2_ = *(const float4*)(hp + 8);
            float4 h3_ = *(const float4*)(hp + 12);
            #pragma unroll
            for (int g = 0; g < 12; ++g) {
                const float* wp = wlds + g * 512 + ks + kk * 16;
                float4 w0 = *(const float4*)(wp + 0);
                float4 w1 = *(const float4*)(wp + 4);
                float4 w2 = *(const float4*)(wp + 8);
                float4 w3 = *(const float4*)(wp + 12);
                a[g] += h0_.x*w0.x + h0_.y*w0.y + h0_.z*w0.z + h0_.w*w0.w
                      + h1_.x*w1.x + h1_.y*w1.y + h1_.z*w1.z + h1_.w*w1.w
                      + h2_.x*w2.x + h2_.y*w2.y + h2_.z*w2.z + h2_.w*w2.w
                      + h3_.x*w3.x + h3_.y*w3.y + h3_.z*w3.z + h3_.w*w3.w;
            }
        }
        #pragma unroll
        for (int g = 0; g < 12; ++g) pl[(v * 12 + g) * 64 + m] = a[g];
        __syncthreads();
        if (v < 4) {
            int c = c0 + v;
            float hr = 0.f, hz = 0.f, hn = 0.f;
            #pragma unroll
            for (int u = 0; u < 8; ++u) {
                hr += pl[(u * 12 + v) * 64 + m];
                hz += pl[(u * 12 + 4 + v) * 64 + m];
                hn += pl[(u * 12 + 8 + v) * 64 + m];
            }
            size_t col = (size_t)tt * 64 + m;
            float ir  = giT[(size_t)c * M + col];
            float iz  = giT[(size_t)(512 + c) * M + col];
            float in_ = giT[(size_t)(1024 + c) * M + col];
            float hold = hprev[c];
            float r = 1.f / (1.f + expf(-(ir + hr + b_r)));
            float z = 1.f / (1.f + expf(-(iz + hz + b_z)));
            float n = tanhf(in_ + r * (hn + b_hn));
            h1buf[(tt & 1) * 32768 + m * 512 + c] = (1.f - z) * n + z * hold;
        }
        grid_barrier(cnt, flag, (unsigned)(tt + 1));
        if (w < 64) {
            const float* hrow = h1buf + (tt & 1) * 32768 + w * 512;
            int o = tid >> 5, s = tid & 31;
            const float* hp = hrow + s * 16;
            float4 ha = *(const float4*)(hp + 0);
            float4 hb = *(const float4*)(hp + 4);
            float4 hc = *(const float4*)(hp + 8);
            float4 hd = *(const float4*)(hp + 12);
            const float* fp = fcw + o * 512 + s * 16;
            float4 fa = *(const float4*)(fp + 0);
            float4 fb = *(const float4*)(fp + 4);
            float4 fc_ = *(const float4*)(fp + 8);
            float4 fd = *(const float4*)(fp + 12);
            float p = ha.x*fa.x + ha.y*fa.y + ha.z*fa.z + ha.w*fa.w
                    + hb.x*fb.x + hb.y*fb.y + hb.z*fb.z + hb.w*fb.w
                    + hc.x*fc_.x + hc.y*fc_.y + hc.z*fc_.z + hc.w*fc_.w
                    + hd.x*fd.x + hd.y*fd.y + hd.z*fd.z + hd.w*fd.w;
            p += __shfl_xor(p, 16);
            p += __shfl_xor(p, 8);
            p += __shfl_xor(p, 4);
            p += __shfl_xor(p, 2);
            p += __shfl_xor(p, 1);
            if (s == 0) apre[o] = p;
            __syncthreads();
            if (tid < J_SZ) {
                float a0 = 1.f / (1.f + expf(-(apre[2 * tid] + fb0)));
                float a1 = 1.f / (1.f + expf(-(apre[2 * tid + 1] + fb1)));
                float F0 = (100.f + 2000.f * a0) * (0.06f + 0.006f * a0 + 0.05f * th);
                float F1 = (100.f + 2000.f * a1) * (0.06f + 0.006f * a1 - 0.05f * th);
                float tau = 0.05f * (F1 - F0);
                float acc = (tau - 5.f * th - 0.3f * om) * 250.f;
                om += (1.f / 60.f) * acc;
                th += (1.f / 60.f) * om;
                out[((size_t)w * T_SZ + t0 + tt) * J_SZ + tid] = th;
            }
        }
    }
    if (tid < J_SZ && w < 64) {
        ths[w * J_SZ + tid] = th;
        oms[w * J_SZ + tid] = om;
    }
}

// ---------------------------------------------------------------------------
extern "C" void kernel_launch(void* const* d_in, const int* in_sizes, int n_in,
                              void* d_out, int out_size, void* d_ws, size_t ws_size,
                              hipStream_t stream) {
    const float* x     = (const float*)d_in[0];
    const float* W_ih0 = (const float*)d_in[1];
    const float* W_hh0 = (const float*)d_in[2];
    const float* b_ih0 = (const float*)d_in[3];
    const float* b_hh0 = (const float*)d_in[4];
    const float* W_ih1 = (const float*)d_in[5];
    const float* W_hh1 = (const float*)d_in[6];
    const float* b_ih1 = (const float*)d_in[7];
    const float* b_hh1 = (const float*)d_in[8];
    const float* fc_W  = (const float*)d_in[9];
    const float* fc_b  = (const float*)d_in[10];
    const float* h0    = (const float*)d_in[11];
    const float* th0   = (const float*)d_in[12];
    const float* om0   = (const float*)d_in[13];
    float* out = (float*)d_out;

    // pick chunk length TC from ws_size
    const size_t fixedf = 65536 + 512 + 512;           // h1buf + ths + oms (floats)
    int TC = 8;
    const int cands[5] = {128, 64, 32, 16, 8};
    for (int ci = 0; ci < 5; ++ci) {
        size_t need = ((size_t)cands[ci] * 64 * (512 + 1536) + fixedf) * 4 + 4096;
        if (need <= ws_size) { TC = cands[ci]; break; }
    }
    float* ws   = (float*)d_ws;
    float* h0c  = ws;
    float* giT  = h0c + (size_t)TC * 64 * 512;
    float* h1bf = giT + (size_t)TC * 64 * 1536;
    float* ths  = h1bf + 65536;
    float* oms  = ths + 512;
    unsigned* bar = (unsigned*)(oms + 512);            // 512 uints zeroed

    k_init<<<262, 256, 0, stream>>>(h0, th0, om0, h0c, h1bf, ths, oms, bar, TC);

    int NC = T_SZ / TC;
    for (int ci = 0; ci < NC; ++ci) {
        int t0 = ci * TC;
        unsigned* cA = bar + (size_t)(2 * ci) * 4;
        unsigned* fA = cA + 2;
        unsigned* cB = bar + (size_t)(2 * ci + 1) * 4;
        unsigned* fB = cB + 2;
        {
            void* args[] = {(void*)&x, (void*)&W_hh0, (void*)&W_ih0, (void*)&b_ih0,
                            (void*)&b_hh0, (void*)&h0c, (void*)&cA, (void*)&fA,
                            (void*)&t0, (void*)&TC};
            (void)hipLaunchCooperativeKernel((void*)k_pass_a, dim3(NWG), dim3(NTH),
                                             args, 0, stream);
        }
        int M = TC * 64;
        k_gemm<<<dim3(M / 128, 12), 256, 0, stream>>>(h0c, W_ih1, b_ih1, giT, M);
        {
            void* args[] = {(void*)&giT, (void*)&W_hh1, (void*)&b_hh1, (void*)&fc_W,
                            (void*)&fc_b, (void*)&h1bf, (void*)&ths, (void*)&oms,
                            (void*)&out, (void*)&cB, (void*)&fB, (void*)&t0, (void*)&TC};
            (void)hipLaunchCooperativeKernel((void*)k_pass_b, dim3(NWG), dim3(NTH),
                                             args, 0, stream);
        }
    }
}